// Round 11
// baseline (6239.188 us; speedup 1.0000x reference)
//
#include <hip/hip_runtime.h>

#define U_N 100000
#define I_N 50000
#define N_NODES 150000
#define EMB_D 64
#define NNZ 4800000
#define ND (N_NODES * EMB_D)          /* 9,600,000 */
#define ND4 (ND / 4)
#define UD4 (U_N * EMB_D / 4)

#define RPB 256                               /* rows per bucket (64 KB f32 tile) */
#define NB ((N_NODES + RPB - 1) / RPB)        /* 586 buckets */
#define TILE 4096                             /* edges per partition tile */
#define NTILE ((NNZ + TILE - 1) / TILE)       /* 1172 */
#define HTILE 4096                            /* edges per hist tile */
#define NHT ((NNZ + HTILE - 1) / HTILE)       /* 1172 */
#define GRID_INIT ((ND4 + 255) / 256)         /* 9375 */

__device__ __forceinline__ unsigned short f2bf(float f) {
    unsigned int u = __float_as_uint(f);
    unsigned int r = (u + 0x7FFFu + ((u >> 16) & 1u)) >> 16;
    return (unsigned short)r;
}
__device__ __forceinline__ float bf2f(unsigned short h) {
    return __uint_as_float((unsigned int)h << 16);
}

// ---- fused: emb0 = concat(u,i); hb0 = bf16(emb0)  ||  bucket histogram ----
__global__ void k_init_hist(const float4* __restrict__ u, const float4* __restrict__ it,
                            float4* __restrict__ emb0, ushort4* __restrict__ hb0,
                            const int4* __restrict__ row4, int* __restrict__ bhist) {
    int blk = blockIdx.x;
    if (blk < GRID_INIT) {
        int i = blk * 256 + threadIdx.x;
        if (i >= ND4) return;
        float4 v = (i < UD4) ? u[i] : it[i - UD4];
        emb0[i] = v;
        ushort4 h;
        h.x = f2bf(v.x); h.y = f2bf(v.y); h.z = f2bf(v.z); h.w = f2bf(v.w);
        hb0[i] = h;
    } else {
        __shared__ int lh[4][NB];                   // per-wave copies, 9.4 KB
        int t = threadIdx.x, wv = t >> 6;           // 4 waves
        for (int i = t; i < 4 * NB; i += 256) ((int*)lh)[i] = 0;
        __syncthreads();
        int base = (blk - GRID_INIT) * (HTILE / 4);
        int cnt = min(HTILE / 4, NNZ / 4 - base);
        for (int i = t; i < cnt; i += 256) {
            int4 r = row4[base + i];
            atomicAdd(&lh[wv][r.x >> 8], 1);
            atomicAdd(&lh[wv][r.y >> 8], 1);
            atomicAdd(&lh[wv][r.z >> 8], 1);
            atomicAdd(&lh[wv][r.w >> 8], 1);
        }
        __syncthreads();
        for (int i = t; i < NB; i += 256) {
            int s = lh[0][i] + lh[1][i] + lh[2][i] + lh[3][i];
            if (s) atomicAdd(&bhist[i], s);
        }
    }
}

// parallel exclusive scan over NB (=586) entries, single 1024-thr block
__global__ void k_bucket_scan(const int* __restrict__ bhist, int* __restrict__ bbase,
                              int* __restrict__ bcur) {
    __shared__ int wsum[16];
    int t = threadIdx.x, lane = t & 63, wv = t >> 6;
    int v = (t < NB) ? bhist[t] : 0;
    int iv = v;
    for (int off = 1; off < 64; off <<= 1) {
        int u = __shfl_up(iv, off);
        if (lane >= off) iv += u;
    }
    if (lane == 63) wsum[wv] = iv;
    __syncthreads();
    int woff = 0;
    for (int w = 0; w < wv; ++w) woff += wsum[w];
    int ex = woff + iv - v;
    if (t < NB) { bbase[t] = ex; bcur[t] = ex; }
    if (t == NB - 1) bbase[NB] = ex + v;
}

// ---------------- phase A: LDS-staged partition into 586 buckets ------------
// 512 thr, 8 edges/thread, 4-way privatized hist (wave-pairs share a copy).
// tmp[p] = { (row_local<<18)|col , val_bits } grouped (unordered) by bucket
__global__ void k_partition(const int* __restrict__ row, const int* __restrict__ col,
                            const float* __restrict__ vals, int* __restrict__ bcur,
                            int2* __restrict__ tmp) {
    __shared__ int2 stage[TILE];                    // 32 KB
    __shared__ unsigned short stageB[TILE];         // 8 KB
    __shared__ int whist[4][NB];                    // 9.4 KB
    __shared__ int cumw[4][NB];                     // 9.4 KB
    __shared__ int scn[NB];                         // 2.3 KB
    __shared__ int gbase[NB];                       // 2.3 KB
    __shared__ int wsum[8];
    int t = threadIdx.x;
    int lane = t & 63, wv = t >> 6;                 // 8 waves
    int cp = wv >> 1;                               // 4 copies
    for (int i = t; i < 4 * NB; i += 512) ((int*)whist)[i] = 0;
    __syncthreads();
    int base = blockIdx.x * TILE;
    int cnt = min(TILE, NNZ - base);

    int  myb[8];
    int  myslot[8];
    int2 myp[8];
#pragma unroll
    for (int j = 0; j < 8; ++j) {
        int i = t + j * 512;
        myb[j] = -1;
        if (i < cnt) {
            int e = base + i;
            int r = row[e];
            int b = r >> 8;
            myb[j] = b;
            myp[j] = make_int2(((r & (RPB - 1)) << 18) | col[e], __float_as_int(vals[e]));
            myslot[j] = atomicAdd(&whist[cp][b], 1);
        }
    }
    __syncthreads();
    // chunked (512-wide) shuffle scan of bucket totals -> scn; merge cumw
    int carry = 0;
    for (int c0 = 0; c0 < NB; c0 += 512) {
        int idx = c0 + t;
        int v = 0;
        if (idx < NB) {
            int run = 0;
#pragma unroll
            for (int w = 0; w < 4; ++w) {
                cumw[w][idx] = run;
                run += whist[w][idx];
            }
            v = run;
        }
        int iv = v;
        for (int off = 1; off < 64; off <<= 1) {
            int u = __shfl_up(iv, off);
            if (lane >= off) iv += u;
        }
        if (lane == 63) wsum[wv] = iv;
        __syncthreads();
        int woff = 0;
        for (int w = 0; w < wv; ++w) woff += wsum[w];
        if (idx < NB) scn[idx] = carry + woff + iv - v;
        int tot = 0;
#pragma unroll
        for (int w = 0; w < 8; ++w) tot += wsum[w];
        carry += tot;
        __syncthreads();
    }
    for (int idx = t; idx < NB; idx += 512) {
        int v = cumw[3][idx] + whist[3][idx];
        if (v > 0) gbase[idx] = atomicAdd(&bcur[idx], v);
    }
    __syncthreads();
#pragma unroll
    for (int j = 0; j < 8; ++j) {
        if (myb[j] >= 0) {
            int b = myb[j];
            int pos = scn[b] + cumw[cp][b] + myslot[j];
            stage[pos] = myp[j];
            stageB[pos] = (unsigned short)b;
        }
    }
    __syncthreads();
    for (int i = t; i < cnt; i += 512) {
        int b = stageB[i];
        tmp[gbase[b] + (i - scn[b])] = stage[i];
    }
}

// ---------------- push SpMM: bucket tile in LDS, ds_add_f32 -----------------
// 16 waves stream depth-16 edge chunks (wave-uniform s_load); each lane
// gathers x[col*64+lane] (contiguous 128B/row) and HW-fp-atomic-adds into the
// 256-row f32 tile. No row sort, no rp. (Round-1 structure; CAS fixed via
// unsafeAtomicAdd; residency fixed via launch_bounds -> 2 blocks/CU.)
__device__ __forceinline__ void push_accum(float* accum, int s0, int s1,
                                           const int2* __restrict__ tmp,
                                           const unsigned short* __restrict__ x,
                                           int t) {
    int lane = t & 63;
    int wid = __builtin_amdgcn_readfirstlane(t >> 6);   // 16 waves
    for (int e = s0 + wid * 16; e < s1; e += 256) {
        int2 E[16];
#pragma unroll
        for (int j = 0; j < 16; ++j) {
            E[j] = tmp[e + j];                  // over-read <=15 lands in hb regions
            if (e + j >= s1) { E[j].x = 0; E[j].y = 0; }
        }
        float g[16];
#pragma unroll
        for (int j = 0; j < 16; ++j)
            g[j] = bf2f(x[(size_t)(E[j].x & 0x3FFFF) * EMB_D + lane]);
#pragma unroll
        for (int j = 0; j < 16; ++j)
            unsafeAtomicAdd(&accum[((((unsigned)E[j].x) >> 18) << 6) | lane],
                            __int_as_float(E[j].y) * g[j]);
    }
}

// layers 1,2: y = bf16(spmm(x))
__global__ __launch_bounds__(1024, 8) void k_spmm_mid(const int* __restrict__ bbase,
                                                      const int2* __restrict__ tmp,
                                                      const unsigned short* __restrict__ x,
                                                      unsigned short* __restrict__ y) {
    __shared__ float accum[RPB * EMB_D];                // 64 KB
    int b = blockIdx.x, t = threadIdx.x;
    float4* a4 = (float4*)accum;
    for (int i = t; i < RPB * EMB_D / 4; i += 1024) a4[i] = make_float4(0.f, 0.f, 0.f, 0.f);
    int s0 = bbase[b], s1 = bbase[b + 1];
    __syncthreads();
    push_accum(accum, s0, s1, tmp, x, t);
    __syncthreads();
    int base = b * (RPB * EMB_D);
    int nel = min(RPB * EMB_D, ND - base);              // last bucket: 240 rows
    ushort2* y2p = (ushort2*)(y + base);
    for (int i = t; i < (nel >> 1); i += 1024) {
        ushort2 h;
        h.x = f2bf(accum[2 * i]);
        h.y = f2bf(accum[2 * i + 1]);
        y2p[i] = h;
    }
}

// layer 3: acc = (emb0 + y1 + x + s) * 0.25   (x == hb2, y1 == hb1)
__global__ __launch_bounds__(1024, 8) void k_spmm_fin(const int* __restrict__ bbase,
                                                      const int2* __restrict__ tmp,
                                                      const unsigned short* __restrict__ x,
                                                      const float* __restrict__ emb0,
                                                      const unsigned short* __restrict__ y1,
                                                      float* __restrict__ acc) {
    __shared__ float accum[RPB * EMB_D];                // 64 KB
    int b = blockIdx.x, t = threadIdx.x;
    float4* a4 = (float4*)accum;
    for (int i = t; i < RPB * EMB_D / 4; i += 1024) a4[i] = make_float4(0.f, 0.f, 0.f, 0.f);
    int s0 = bbase[b], s1 = bbase[b + 1];
    __syncthreads();
    push_accum(accum, s0, s1, tmp, x, t);
    __syncthreads();
    int base = b * (RPB * EMB_D);
    int nel = min(RPB * EMB_D, ND - base);
    const float4*  e4  = (const float4*)(emb0 + base);
    const ushort4* h14 = (const ushort4*)(y1 + base);
    const ushort4* x4  = (const ushort4*)(x + base);
    float4* o4 = (float4*)(acc + base);
    for (int i = t; i < (nel >> 2); i += 1024) {
        float4 e = e4[i];
        ushort4 h1 = h14[i];
        ushort4 h2 = x4[i];
        float4 r;
        r.x = (e.x + bf2f(h1.x) + bf2f(h2.x) + accum[4 * i + 0]) * 0.25f;
        r.y = (e.y + bf2f(h1.y) + bf2f(h2.y) + accum[4 * i + 1]) * 0.25f;
        r.z = (e.z + bf2f(h1.z) + bf2f(h2.z) + accum[4 * i + 2]) * 0.25f;
        r.w = (e.w + bf2f(h1.w) + bf2f(h2.w) + accum[4 * i + 3]) * 0.25f;
        o4[i] = r;
    }
}

extern "C" void kernel_launch(void* const* d_in, const int* in_sizes, int n_in,
                              void* d_out, int out_size, void* d_ws, size_t ws_size,
                              hipStream_t stream) {
    const float* user_emb = (const float*)d_in[0];
    const float* item_emb = (const float*)d_in[1];
    const int*   row      = (const int*)d_in[2];
    const int*   col      = (const int*)d_in[3];
    const float* vals     = (const float*)d_in[4];

    float* emb0 = (float*)d_out;            // [ND] output 0
    float* acc  = (float*)d_out + ND;       // [ND] output 1

    // ws: [tmp int2[NNZ] (live through all layers) | hb0 | hb1 | hb2 | ints]
    int2* tmp = (int2*)d_ws;
    unsigned short* hb0 = (unsigned short*)(tmp + NNZ);   // [ND]
    unsigned short* hb1 = hb0 + ND;                       // [ND]
    unsigned short* hb2 = hb1 + ND;                       // [ND]
    int* bhist = (int*)(hb2 + ND);           // [NB]
    int* bbase = bhist + NB;                 // [NB+1]
    int* bcur  = bbase + NB + 1;             // [NB]

    const int BLK = 256;

    // --- build: fused init+hist -> scan -> partition (no row sort) ---
    hipMemsetAsync(bhist, 0, NB * sizeof(int), stream);
    k_init_hist<<<GRID_INIT + NHT, BLK, 0, stream>>>(
        (const float4*)user_emb, (const float4*)item_emb,
        (float4*)emb0, (ushort4*)hb0, (const int4*)row, bhist);
    k_bucket_scan<<<1, 1024, 0, stream>>>(bhist, bbase, bcur);
    k_partition<<<NTILE, 512, 0, stream>>>(row, col, vals, bcur, tmp);

    // --- 3 propagation layers, push-accumulate, acc fused into final ---
    k_spmm_mid<<<NB, 1024, 0, stream>>>(bbase, tmp, hb0, hb1);
    k_spmm_mid<<<NB, 1024, 0, stream>>>(bbase, tmp, hb1, hb2);
    k_spmm_fin<<<NB, 1024, 0, stream>>>(bbase, tmp, hb2, emb0, hb1, acc);
}

// Round 12
// 570.568 us; speedup vs baseline: 10.9351x; 10.9351x over previous
//
#include <hip/hip_runtime.h>

#define U_N 100000
#define I_N 50000
#define N_NODES 150000
#define EMB_D 64
#define NNZ 4800000
#define ND (N_NODES * EMB_D)          /* 9,600,000 */
#define ND4 (ND / 4)
#define UD4 (U_N * EMB_D / 4)

#define RPB 1024                              /* rows per bucket */
#define NB ((N_NODES + RPB - 1) / RPB)        /* 147 buckets */
#define TILE 4096                             /* edges per partition tile */
#define NTILE ((NNZ + TILE - 1) / TILE)       /* 1172 */
#define HTILE 4096                            /* edges per hist tile */
#define NHT ((NNZ + HTILE - 1) / HTILE)       /* 1172 */

__device__ __forceinline__ unsigned short f2bf(float f) {
    unsigned int u = __float_as_uint(f);
    unsigned int r = (u + 0x7FFFu + ((u >> 16) & 1u)) >> 16;
    return (unsigned short)r;
}
__device__ __forceinline__ float bf2f(unsigned short h) {
    return __uint_as_float((unsigned int)h << 16);
}

// emb0 = concat(u,i); hb0 = bf16(emb0)
__global__ void k_init(const float4* __restrict__ u, const float4* __restrict__ it,
                       float4* __restrict__ emb0, ushort4* __restrict__ hb0) {
    int i = blockIdx.x * blockDim.x + threadIdx.x;
    if (i >= ND4) return;
    float4 v = (i < UD4) ? u[i] : it[i - UD4];
    emb0[i] = v;
    ushort4 h;
    h.x = f2bf(v.x); h.y = f2bf(v.y); h.z = f2bf(v.z); h.w = f2bf(v.w);
    hb0[i] = h;
}

// ---------------- bucket histogram (LDS-staged, privatized, int4) ----------
__global__ void k_bucket_hist(const int4* __restrict__ row4, int* __restrict__ bhist) {
    __shared__ int lh[4][NB];                       // per-wave copies
    int t = threadIdx.x, wv = t >> 6;               // 4 waves
    for (int i = t; i < 4 * NB; i += 256) ((int*)lh)[i] = 0;
    __syncthreads();
    int base = blockIdx.x * (HTILE / 4);
    int cnt = min(HTILE / 4, NNZ / 4 - base);
    for (int i = t; i < cnt; i += 256) {
        int4 r = row4[base + i];
        atomicAdd(&lh[wv][r.x >> 10], 1);
        atomicAdd(&lh[wv][r.y >> 10], 1);
        atomicAdd(&lh[wv][r.z >> 10], 1);
        atomicAdd(&lh[wv][r.w >> 10], 1);
    }
    __syncthreads();
    for (int i = t; i < NB; i += 256) {
        int s = lh[0][i] + lh[1][i] + lh[2][i] + lh[3][i];
        if (s) atomicAdd(&bhist[i], s);
    }
}

// parallel exclusive scan over NB (=147) entries, wave-shuffle based
__global__ void k_bucket_scan(const int* __restrict__ bhist, int* __restrict__ bbase,
                              int* __restrict__ bcur) {
    __shared__ int wsum[4];
    int t = threadIdx.x, lane = t & 63, wv = t >> 6;
    int v = (t < NB) ? bhist[t] : 0;
    int iv = v;
    for (int off = 1; off < 64; off <<= 1) {
        int u = __shfl_up(iv, off);
        if (lane >= off) iv += u;
    }
    if (lane == 63) wsum[wv] = iv;
    __syncthreads();
    int woff = 0;
    for (int w = 0; w < wv; ++w) woff += wsum[w];
    int ex = woff + iv - v;
    if (t < NB) { bbase[t] = ex; bcur[t] = ex; }
    if (t == NB - 1) bbase[NB] = ex + v;
}

// ---------------- phase A: LDS-staged partition into 147 buckets ------------
// 512 thr, 8 edges/thread, per-wave privatized hist (contention /8).
// tmp[p] = { (row_local<<18)|col , val_bits } grouped (unordered) by bucket
__global__ void k_partition(const int* __restrict__ row, const int* __restrict__ col,
                            const float* __restrict__ vals, int* __restrict__ bcur,
                            int2* __restrict__ tmp) {
    __shared__ int2 stage[TILE];                    // 32 KB
    __shared__ unsigned char stageB[TILE];          // 4 KB
    __shared__ int whist[8][NB];                    // per-wave hists
    __shared__ int cumw[8][NB];                     // per-wave exclusive bases
    __shared__ int scn[NB];
    __shared__ int gbase[NB];
    __shared__ int wsum[8];
    int t = threadIdx.x;
    int lane = t & 63, wv = t >> 6;                 // 8 waves
    for (int i = t; i < 8 * NB; i += 512) ((int*)whist)[i] = 0;
    __syncthreads();
    int base = blockIdx.x * TILE;
    int cnt = min(TILE, NNZ - base);

    int  myb[8];
    int  myslot[8];
    int2 myp[8];
#pragma unroll
    for (int j = 0; j < 8; ++j) {
        int i = t + j * 512;
        myb[j] = -1;
        if (i < cnt) {
            int e = base + i;
            int r = row[e];
            int b = r >> 10;
            myb[j] = b;
            myp[j] = make_int2(((r & (RPB - 1)) << 18) | col[e], __float_as_int(vals[e]));
            myslot[j] = atomicAdd(&whist[wv][b], 1);
        }
    }
    __syncthreads();
    // merge per-wave hists -> per-wave exclusive bases + bucket totals
    int v = 0;
    if (t < NB) {
        int run = 0;
#pragma unroll
        for (int w = 0; w < 8; ++w) {
            cumw[w][t] = run;
            run += whist[w][t];
        }
        v = run;
    }
    int iv = v;
    for (int off = 1; off < 64; off <<= 1) {
        int u = __shfl_up(iv, off);
        if (lane >= off) iv += u;
    }
    if (lane == 63) wsum[wv] = iv;
    __syncthreads();
    int woff = 0;
    for (int w = 0; w < wv; ++w) woff += wsum[w];
    if (t < NB) scn[t] = woff + iv - v;
    if (t < NB && v > 0) gbase[t] = atomicAdd(&bcur[t], v);
    __syncthreads();
#pragma unroll
    for (int j = 0; j < 8; ++j) {
        if (myb[j] >= 0) {
            int b = myb[j];
            int pos = scn[b] + cumw[wv][b] + myslot[j];
            stage[pos] = myp[j];
            stageB[pos] = (unsigned char)b;
        }
    }
    __syncthreads();
    for (int i = t; i < cnt; i += 512) {
        int b = stageB[i];
        tmp[gbase[b] + (i - scn[b])] = stage[i];
    }
}

// ---------------- phase B: per-bucket exact CSR, 1024 thr -------------------
// pass 1: privatized x4 LDS row-hist; shuffle scan -> rp; pass 2: counting sort
__global__ void k_bucket_csr(const int* __restrict__ bbase, const int2* __restrict__ tmp,
                             int2* __restrict__ edges, int* __restrict__ rp) {
    __shared__ int ph[4][RPB];                      // 16 KB privatized hists
    __shared__ int lex[RPB];                        // global row cursors
    __shared__ int wsum[16];
    int b = blockIdx.x, t = threadIdx.x;            // 1024 threads, 16 waves
    int lane = t & 63, wv = t >> 6;
    int s0 = bbase[b], s1 = bbase[b + 1];
    int n = s1 - s0;
    for (int i = t; i < 4 * RPB; i += 1024) ((int*)ph)[i] = 0;
    __syncthreads();
    int cp = wv >> 2;                               // 4 waves per copy
    for (int i = t; i < n; i += 1024)
        atomicAdd(&ph[cp][(unsigned)tmp[s0 + i].x >> 18], 1);
    __syncthreads();
    int v = ph[0][t] + ph[1][t] + ph[2][t] + ph[3][t];
    int iv = v;
    for (int off = 1; off < 64; off <<= 1) {
        int u = __shfl_up(iv, off);
        if (lane >= off) iv += u;
    }
    if (lane == 63) wsum[wv] = iv;
    __syncthreads();
    int woff = 0;
    for (int w = 0; w < wv; ++w) woff += wsum[w];
    int excl = woff + iv - v;                       // exclusive prefix within bucket
    int r = b * RPB + t;
    if (r < N_NODES) rp[r] = s0 + excl;
    if (b == NB - 1 && t == 0) rp[N_NODES] = NNZ;
    lex[t] = s0 + excl;                             // global cursor
    __syncthreads();
    for (int i = t; i < n; i += 1024) {
        int2 p = tmp[s0 + i];
        int rl = (unsigned)p.x >> 18;
        int pos = atomicAdd(&lex[rl], 1);
        edges[pos] = make_int2(p.x & 0x3FFFF, p.y);
    }
}

// ---------------- pull SpMM, one wave per row, lane = dim, bf16 gather ------
// 16 gathers in flight per wave; edge loads are wave-uniform -> s_load path.
// Tail handled by one masked 16-chunk (col->0, val->0), never a serial loop.
__device__ __forceinline__ float row_dot(const int* __restrict__ rp,
                                         const int2* __restrict__ edges,
                                         const unsigned short* __restrict__ x,
                                         int wid, int lane) {
    int start = __builtin_amdgcn_readfirstlane(rp[wid]);
    int end   = __builtin_amdgcn_readfirstlane(rp[wid + 1]);
    float s0 = 0.f, s1 = 0.f, s2 = 0.f, s3 = 0.f;
    int e = start;
    for (; e + 16 <= end; e += 16) {
        int2 E[16];
#pragma unroll
        for (int j = 0; j < 16; ++j) E[j] = edges[e + j];
        float g[16];
#pragma unroll
        for (int j = 0; j < 16; ++j) g[j] = bf2f(x[(size_t)E[j].x * EMB_D + lane]);
#pragma unroll
        for (int j = 0; j < 16; ++j) {
            float p = __int_as_float(E[j].y) * g[j];
            if ((j & 3) == 0) s0 += p;
            else if ((j & 3) == 1) s1 += p;
            else if ((j & 3) == 2) s2 += p;
            else s3 += p;
        }
    }
    int rem = end - e;
    if (rem > 0) {
        // over-reads <=15 int2 past rp[N]; lands in allocated ws, masked below
        int2 E[16];
#pragma unroll
        for (int j = 0; j < 16; ++j) E[j] = edges[e + j];
#pragma unroll
        for (int j = 0; j < 16; ++j)
            if (j >= rem) { E[j].x = 0; E[j].y = 0; }
        float g[16];
#pragma unroll
        for (int j = 0; j < 16; ++j) g[j] = bf2f(x[(size_t)E[j].x * EMB_D + lane]);
#pragma unroll
        for (int j = 0; j < 16; ++j) {
            float p = __int_as_float(E[j].y) * g[j];
            if ((j & 3) == 0) s0 += p;
            else if ((j & 3) == 1) s1 += p;
            else if ((j & 3) == 2) s2 += p;
            else s3 += p;
        }
    }
    return (s0 + s1) + (s2 + s3);
}

// layers 1,2: y = bf16(spmm(x)) only
__global__ void k_spmm_mid(const int* __restrict__ rp, const int2* __restrict__ edges,
                           const unsigned short* __restrict__ x,
                           unsigned short* __restrict__ y) {
    int wid = blockIdx.x * (blockDim.x >> 6) + (threadIdx.x >> 6);
    if (wid >= N_NODES) return;
    int lane = threadIdx.x & 63;
    float s = row_dot(rp, edges, x, wid, lane);
    y[(size_t)wid * EMB_D + lane] = f2bf(s);
}

// layer 3: acc = (emb0 + y1 + y2 + s) * 0.25
__global__ void k_spmm_fin(const int* __restrict__ rp, const int2* __restrict__ edges,
                           const unsigned short* __restrict__ x,
                           const float* __restrict__ emb0,
                           const unsigned short* __restrict__ y1,
                           const unsigned short* __restrict__ y2,
                           float* __restrict__ acc) {
    int wid = blockIdx.x * (blockDim.x >> 6) + (threadIdx.x >> 6);
    if (wid >= N_NODES) return;
    int lane = threadIdx.x & 63;
    float s = row_dot(rp, edges, x, wid, lane);
    size_t o = (size_t)wid * EMB_D + lane;
    acc[o] = (emb0[o] + bf2f(y1[o]) + bf2f(y2[o]) + s) * 0.25f;
}

extern "C" void kernel_launch(void* const* d_in, const int* in_sizes, int n_in,
                              void* d_out, int out_size, void* d_ws, size_t ws_size,
                              hipStream_t stream) {
    const float* user_emb = (const float*)d_in[0];
    const float* item_emb = (const float*)d_in[1];
    const int*   row      = (const int*)d_in[2];
    const int*   col      = (const int*)d_in[3];
    const float* vals     = (const float*)d_in[4];

    float* emb0 = (float*)d_out;            // [ND] output 0
    float* acc  = (float*)d_out + ND;       // [ND] output 1

    // ws: [tmp int2[NNZ] | edges int2[NNZ] | hb2 ushort[ND] | ints]
    // tmp (38.4 MB) is dead after k_bucket_csr -> reused as hb0/hb1 bf16
    int2* tmp   = (int2*)d_ws;
    int2* edges = tmp + NNZ;
    unsigned short* hb2 = (unsigned short*)(edges + NNZ);   // [ND]
    int*  ibase = (int*)(hb2 + ND);
    int*  rp    = ibase;                     // [N_NODES+1]
    int*  bhist = ibase + N_NODES + 1;       // [NB]
    int*  bbase = bhist + NB;                // [NB+1]
    int*  bcur  = bbase + NB + 1;            // [NB]
    unsigned short* hb0 = (unsigned short*)d_ws;   // [ND] aliases tmp
    unsigned short* hb1 = hb0 + ND;                // [ND]

    const int BLK = 256;
    const int grid_nd = (ND4 + BLK - 1) / BLK;
    const int grid_spmm = (N_NODES * 64 + BLK - 1) / BLK;  // 1 wave per row

    // --- CSR build: hist -> scan -> partition -> per-bucket sort ---
    hipMemsetAsync(bhist, 0, NB * sizeof(int), stream);
    k_bucket_hist<<<NHT, BLK, 0, stream>>>((const int4*)row, bhist);
    k_bucket_scan<<<1, BLK, 0, stream>>>(bhist, bbase, bcur);
    k_partition<<<NTILE, 512, 0, stream>>>(row, col, vals, bcur, tmp);
    k_bucket_csr<<<NB, 1024, 0, stream>>>(bbase, tmp, edges, rp);

    // --- init outputs + bf16 layer-0 (overwrites tmp region) ---
    k_init<<<grid_nd, BLK, 0, stream>>>((const float4*)user_emb,
                                        (const float4*)item_emb,
                                        (float4*)emb0, (ushort4*)hb0);

    // --- 3 propagation layers, acc deferred to the final pass ---
    k_spmm_mid<<<grid_spmm, BLK, 0, stream>>>(rp, edges, hb0, hb1);
    k_spmm_mid<<<grid_spmm, BLK, 0, stream>>>(rp, edges, hb1, hb2);
    k_spmm_fin<<<grid_spmm, BLK, 0, stream>>>(rp, edges, hb2, emb0, hb1, hb2, acc);
}